// Round 4
// baseline (638.369 us; speedup 1.0000x reference)
//
#include <hip/hip_runtime.h>
#include <cstdint>
#include <cstddef>

// ---------------------------------------------------------------------------
// MambaBlock fused pipeline for MI355X (gfx950).
// B=4, S=4096, d=1024, n=16. M = 16384 token rows.
// R4: front-end restructured. rowstats_kernel computes LN1 (mean,rstd) once
//     per row (wave-per-row). lnconv_kernel v2 is wave-per-row, consumes the
//     stats table (no redundant 4x LN reductions, no block-wide barriers),
//     single butterfly reduce for lnS. ln_kernel v2 wave-per-row likewise.
//     GEMMs unchanged from R3 (256x256 8-wave, depth-2 pipeline, vmcnt(8)).
// ---------------------------------------------------------------------------

typedef short bf16x8 __attribute__((ext_vector_type(8)));
typedef float f32x4 __attribute__((ext_vector_type(4)));

#define GLD16(gp, lp)                                                          \
  __builtin_amdgcn_global_load_lds(                                            \
      (__attribute__((address_space(1))) void*)(gp),                           \
      (__attribute__((address_space(3))) void*)(lp), 16, 0, 0)

static __device__ __forceinline__ ushort f2bf(float f) {
  union { float f; uint32_t u; } c; c.f = f;
  uint32_t r = c.u + 0x7FFFu + ((c.u >> 16) & 1u);
  return (ushort)(r >> 16);
}
static __device__ __forceinline__ float bf2f(ushort u) {
  union { uint32_t u; float f; } c; c.u = ((uint32_t)u) << 16;
  return c.f;
}

// ---------- per-row LN stats: one wave per 1024-wide row -------------------
__global__ __launch_bounds__(256) void rowstats_kernel(
    const float* __restrict__ x, float2* __restrict__ stats) {
  const int row = blockIdx.x * 4 + (threadIdx.x >> 6);
  const int lane = threadIdx.x & 63;
  const float4* xr = (const float4*)(x + (size_t)row * 1024);
  float s = 0.f, q = 0.f;
#pragma unroll
  for (int i = 0; i < 4; i++) {
    const float4 v = xr[lane + i * 64];
    s += v.x + v.y + v.z + v.w;
    q += v.x * v.x + v.y * v.y + v.z * v.z + v.w * v.w;
  }
#pragma unroll
  for (int off = 32; off > 0; off >>= 1) {
    s += __shfl_down(s, off);
    q += __shfl_down(q, off);
  }
  if (lane == 0) {
    const float mean = s * (1.f / 1024.f);
    const float var  = q * (1.f / 1024.f) - mean * mean;
    stats[row] = make_float2(mean, rsqrtf(var + 1e-5f));
  }
}

// ---- fused conv front-end, wave-per-row: ln1 via stats -> depthwise -------
// ---- conv(k=4) + residual -> x1; then lnS(x1) -> abuf (bf16). -------------
__global__ __launch_bounds__(256) void lnconv_kernel(
    const float* __restrict__ x, const float2* __restrict__ stats,
    const float* __restrict__ ln1w, const float* __restrict__ ln1b,
    const float* __restrict__ cw, const float* __restrict__ cb,
    const float* __restrict__ lnsw, const float* __restrict__ lnsb,
    float* __restrict__ x1, ushort* __restrict__ abuf) {
  const int row = blockIdx.x * 4 + (threadIdx.x >> 6);  // b*4096 + t
  const int t = row & 4095;
  const int lane = threadIdx.x & 63;
  const float4* x4 = (const float4*)x;

  float2 st[4];
#pragma unroll
  for (int j = 0; j < 4; j++)
    st[j] = (t - 3 + j >= 0) ? stats[row - 3 + j] : make_float2(0.f, 0.f);

  float4 o[4];
  float s = 0.f, q = 0.f;
#pragma unroll
  for (int i = 0; i < 4; i++) {
    const int f4 = lane + i * 64;   // float4 index within row
    const int c0 = f4 * 4;          // channel base
    float4 acc = *(const float4*)(cb + c0);
    const float4 w0 = *(const float4*)(cw + (size_t)(c0 + 0) * 4);
    const float4 w1 = *(const float4*)(cw + (size_t)(c0 + 1) * 4);
    const float4 w2 = *(const float4*)(cw + (size_t)(c0 + 2) * 4);
    const float4 w3 = *(const float4*)(cw + (size_t)(c0 + 3) * 4);
    const float4 wv4 = ((const float4*)ln1w)[f4];
    const float4 bv4 = ((const float4*)ln1b)[f4];
    float4 xm = make_float4(0.f, 0.f, 0.f, 0.f);
#pragma unroll
    for (int j = 0; j < 4; j++) {
      if (t - 3 + j >= 0) {
        const float4 xv = x4[(size_t)(row - 3 + j) * 256 + f4];
        if (j == 3) xm = xv;
        const float mean = st[j].x, rstd = st[j].y;
        const float lx = (xv.x - mean) * rstd * wv4.x + bv4.x;
        const float ly = (xv.y - mean) * rstd * wv4.y + bv4.y;
        const float lz = (xv.z - mean) * rstd * wv4.z + bv4.z;
        const float lw = (xv.w - mean) * rstd * wv4.w + bv4.w;
        acc.x += lx * ((const float*)&w0)[j];
        acc.y += ly * ((const float*)&w1)[j];
        acc.z += lz * ((const float*)&w2)[j];
        acc.w += lw * ((const float*)&w3)[j];
      }
    }
    o[i].x = xm.x + acc.x; o[i].y = xm.y + acc.y;
    o[i].z = xm.z + acc.z; o[i].w = xm.w + acc.w;
    ((float4*)x1)[(size_t)row * 256 + f4] = o[i];
    s += o[i].x + o[i].y + o[i].z + o[i].w;
    q += o[i].x * o[i].x + o[i].y * o[i].y + o[i].z * o[i].z + o[i].w * o[i].w;
  }
  // ---- lnS butterfly reduce (all lanes get total) ----
#pragma unroll
  for (int off = 1; off < 64; off <<= 1) {
    s += __shfl_xor(s, off);
    q += __shfl_xor(q, off);
  }
  const float mean = s * (1.f / 1024.f);
  const float var  = q * (1.f / 1024.f) - mean * mean;
  const float rstd = rsqrtf(var + 1e-5f);
#pragma unroll
  for (int i = 0; i < 4; i++) {
    const int f4 = lane + i * 64;
    const float4 wv4 = ((const float4*)lnsw)[f4];
    const float4 bv4 = ((const float4*)lnsb)[f4];
    ushort4 a;
    a.x = f2bf((o[i].x - mean) * rstd * wv4.x + bv4.x);
    a.y = f2bf((o[i].y - mean) * rstd * wv4.y + bv4.y);
    a.z = f2bf((o[i].z - mean) * rstd * wv4.z + bv4.z);
    a.w = f2bf((o[i].w - mean) * rstd * wv4.w + bv4.w);
    ((ushort4*)(abuf + (size_t)row * 1024))[f4] = a;
  }
}

// ---------------- LayerNorm: one wave per 1024-wide row --------------------
template <int BF16OUT>
__global__ __launch_bounds__(256) void ln_kernel(
    const float* __restrict__ x, const float* __restrict__ w,
    const float* __restrict__ b, void* __restrict__ out) {
  const int row = blockIdx.x * 4 + (threadIdx.x >> 6);
  const int lane = threadIdx.x & 63;
  const float4* xr = (const float4*)(x + (size_t)row * 1024);
  float4 v[4];
  float s = 0.f, q = 0.f;
#pragma unroll
  for (int i = 0; i < 4; i++) {
    v[i] = xr[lane + i * 64];
    s += v[i].x + v[i].y + v[i].z + v[i].w;
    q += v[i].x * v[i].x + v[i].y * v[i].y + v[i].z * v[i].z + v[i].w * v[i].w;
  }
#pragma unroll
  for (int off = 1; off < 64; off <<= 1) {
    s += __shfl_xor(s, off);
    q += __shfl_xor(q, off);
  }
  const float mean = s * (1.f / 1024.f);
  const float var  = q * (1.f / 1024.f) - mean * mean;
  const float rstd = rsqrtf(var + 1e-5f);
#pragma unroll
  for (int i = 0; i < 4; i++) {
    const int f4 = lane + i * 64;
    const float4 wv4 = ((const float4*)w)[f4];
    const float4 bv4 = ((const float4*)b)[f4];
    const float o0 = (v[i].x - mean) * rstd * wv4.x + bv4.x;
    const float o1 = (v[i].y - mean) * rstd * wv4.y + bv4.y;
    const float o2 = (v[i].z - mean) * rstd * wv4.z + bv4.z;
    const float o3 = (v[i].w - mean) * rstd * wv4.w + bv4.w;
    if (BF16OUT) {
      ushort4 o; o.x = f2bf(o0); o.y = f2bf(o1); o.z = f2bf(o2); o.w = f2bf(o3);
      ((ushort4*)((ushort*)out + (size_t)row * 1024))[f4] = o;
    } else {
      float4 o; o.x = o0; o.y = o1; o.z = o2; o.w = o3;
      ((float4*)((float*)out + (size_t)row * 1024))[f4] = o;
    }
  }
}

// ------- merged tiled transpose + fp32->bf16 for all 4 weights -------------
__global__ __launch_bounds__(256) void wt_all_kernel(
    const float* __restrict__ in_w, const float* __restrict__ out_w,
    const float* __restrict__ w1, const float* __restrict__ w2,
    ushort* __restrict__ in_wT, ushort* __restrict__ out_wT,
    ushort* __restrict__ w1T, ushort* __restrict__ w2T) {
  __shared__ float tile[32][33];
  const int idx = blockIdx.x;
  const float* src; ushort* dst; int K, N, n0, k0;
  if (idx < 2048) {
    src = in_w; dst = in_wT; K = 1024; N = 2048;
    n0 = (idx & 63) * 32; k0 = (idx >> 6) * 32;
  } else if (idx < 3072) {
    const int r = idx - 2048;
    src = out_w; dst = out_wT; K = 1024; N = 1024;
    n0 = (r & 31) * 32; k0 = (r >> 5) * 32;
  } else if (idx < 5120) {
    const int r = idx - 3072;
    src = w1; dst = w1T; K = 1024; N = 2048;
    n0 = (r & 63) * 32; k0 = (r >> 6) * 32;
  } else {
    const int r = idx - 5120;
    src = w2; dst = w2T; K = 2048; N = 1024;
    n0 = (r & 31) * 32; k0 = (r >> 5) * 32;
  }
  const int tx = threadIdx.x & 31, ty = threadIdx.x >> 5;
#pragma unroll
  for (int j = 0; j < 32; j += 8)
    tile[ty + j][tx] = src[(size_t)(k0 + ty + j) * N + n0 + tx];
  __syncthreads();
#pragma unroll
  for (int j = 0; j < 32; j += 8)
    dst[(size_t)(n0 + ty + j) * K + k0 + tx] = f2bf(tile[tx][ty + j]);
}

// ------------- u = xp @ xp_w + xp_b via MFMA (N=16) ------------------------
__global__ __launch_bounds__(256) void u_mfma_kernel(
    const ushort* __restrict__ xp, const float* __restrict__ xpw,
    const float* __restrict__ xpb, float* __restrict__ u) {
  __shared__ ushort Ws[16 * 1024];  // W^T bf16, 16B-block swizzled
  __shared__ ushort As[64 * 64];
  const int tid = threadIdx.x;
  const int wave = tid >> 6, lane = tid & 63;
  const int l16 = lane & 15, quad = lane >> 4;
  for (int e = tid; e < 16384; e += 256) {
    const int n = e & 15, k = e >> 4;
    Ws[n * 1024 + (((k >> 3) ^ (n & 7)) << 3) + (k & 7)] =
        f2bf(xpw[(size_t)k * 16 + n]);
  }
  const int bm0 = blockIdx.x * 64;
  const int srow = lane >> 3, sblk = (lane & 7) ^ (srow & 7);
  const ushort* Ag = xp + (size_t)(bm0 + wave * 16 + srow) * 1024 + sblk * 8;
  ushort* Al = &As[wave * 16 * 64];
  const int rsw = l16 & 7;
  f32x4 acc = (f32x4){0.f, 0.f, 0.f, 0.f};
  __syncthreads();
  for (int k0 = 0; k0 < 1024; k0 += 64) {
    GLD16(Ag + k0, Al);
    GLD16(Ag + k0 + (size_t)8 * 1024, Al + 512);
    __syncthreads();
#pragma unroll
    for (int kh = 0; kh < 2; kh++) {
      const bf16x8 aF = *(const bf16x8*)
          &As[(wave * 16 + l16) * 64 + (((kh * 4 + quad) ^ rsw) << 3)];
      const bf16x8 bF = *(const bf16x8*)
          &Ws[l16 * 1024 + ((((k0 >> 3) + kh * 4 + quad) ^ rsw) << 3)];
      acc = __builtin_amdgcn_mfma_f32_16x16x32_bf16(aF, bF, acc, 0, 0, 0);
    }
    __syncthreads();
  }
  const float bv = xpb[l16];
#pragma unroll
  for (int r = 0; r < 4; r++) {
    const int row = bm0 + wave * 16 + quad * 4 + r;
    u[(size_t)row * 16 + l16] = acc[r] + bv;
  }
}

// ------------- selective scan: one block per (b,n) sequence ----------------
__global__ __launch_bounds__(256) void scan_kernel(
    const float* __restrict__ u, const float* __restrict__ A_log,
    float* __restrict__ hs) {
  const int tid = threadIdx.x;
  const int b = blockIdx.x >> 4;
  const int n = blockIdx.x & 15;
  const float d = expf(-expf(A_log[n]));
  const int t0 = tid * 16;
  const float* up = u + ((size_t)b * 4096) * 16 + n;
  float loc[16];
  float h = 0.f;
#pragma unroll
  for (int i = 0; i < 16; i++) {
    h = d * h + up[(size_t)(t0 + i) * 16];
    loc[i] = h;
  }
  __shared__ float sv[256];
  sv[tid] = h;
  __syncthreads();
  float d16 = d * d; d16 *= d16; d16 *= d16; d16 *= d16;  // d^16
  float f = d16;
  for (int off = 1; off < 256; off <<= 1) {
    const float add = (tid >= off) ? sv[tid - off] : 0.f;
    __syncthreads();
    sv[tid] += f * add;
    __syncthreads();
    f *= f;
  }
  const float carry = (tid > 0) ? sv[tid - 1] : 0.f;
  float dp = d;
#pragma unroll
  for (int i = 0; i < 16; i++) {
    const float hg = loc[i] + dp * carry;
    dp *= d;
    // hs layout: (t*4 + b)*16 + n  == GEMM3 row order m' = t*B + b
    hs[((size_t)(t0 + i) * 4 + b) * 16 + n] = hg;
  }
}

// ------------- g[m'] = (hs[m'] @ D) * z[b,t]  -> bf16 ----------------------
__global__ __launch_bounds__(256) void g_kernel(
    const float* __restrict__ hs, const float* __restrict__ Dm,
    const ushort* __restrict__ z, ushort* __restrict__ g) {
  __shared__ float hsh[256];
  const int tid = threadIdx.x;
  const int r0 = blockIdx.x * 16;
  hsh[tid] = hs[(size_t)r0 * 16 + tid];
  __syncthreads();
  float4 acc[16];
#pragma unroll
  for (int rr = 0; rr < 16; rr++) acc[rr] = make_float4(0.f, 0.f, 0.f, 0.f);
  const float4* Dv = (const float4*)Dm;
#pragma unroll
  for (int n = 0; n < 16; n++) {
    const float4 dv = Dv[(size_t)n * 256 + tid];
#pragma unroll
    for (int rr = 0; rr < 16; rr++) {
      const float h = hsh[rr * 16 + n];
      acc[rr].x += h * dv.x; acc[rr].y += h * dv.y;
      acc[rr].z += h * dv.z; acc[rr].w += h * dv.w;
    }
  }
#pragma unroll
  for (int rr = 0; rr < 16; rr++) {
    const int r = r0 + rr;
    const int b = r & 3, t = r >> 2;
    const ushort4 zv =
        *(const ushort4*)(z + ((size_t)b * 4096 + t) * 1024 + tid * 4);
    ushort4 o;
    o.x = f2bf(acc[rr].x * bf2f(zv.x)); o.y = f2bf(acc[rr].y * bf2f(zv.y));
    o.z = f2bf(acc[rr].z * bf2f(zv.z)); o.w = f2bf(acc[rr].w * bf2f(zv.w));
    *(ushort4*)(g + (size_t)r * 1024 + tid * 4) = o;
  }
}

// ------------- bf16 MFMA GEMM: C = A(MxK) @ Bt(NxK)^T + bias, epilogues ----
// 256x256 tile, BK=64, 8 waves (2Mx4N), 4 phases/K-tile, dbuf 128KiB LDS.
// Depth-2 pipeline: all 8 staging loads of tile t+2 at P3 of tile t,
// boundary vmcnt(8). Swapped mfma operands -> D^T fragments, vector stores.
// EPI 0: split N=2048 -> silu->xp bf16 (col<1024), sigmoid->z bf16
// EPI 1: in-place flat residual add | EPI 2: gelu->bf16 | EPI 3: p1+v->p0
template <int EPI>
__global__ __launch_bounds__(512, 2) void gemm_bt(
    const ushort* __restrict__ A, const ushort* __restrict__ Bt,
    const float* __restrict__ bias, int K, void* __restrict__ p0,
    void* __restrict__ p1) {
  __shared__ __align__(16) ushort sm[65536];  // [2 bufs][A 16384 | B 16384]
  const int tid = threadIdx.x;
  const int wave = tid >> 6, lane = tid & 63;
  const int l16 = lane & 15, quad = lane >> 4;
  const int wm = wave >> 2, wn = wave & 3;  // 2 x 4 wave grid

  const int nbx = (int)gridDim.x;
  int tm, tn;
  if ((nbx & 7) == 0) {
    const int lid = (int)blockIdx.y * nbx + (int)blockIdx.x;
    const int ncm = nbx >> 3;
    const int xcd = lid & 7;
    const int j = lid >> 3;
    tm = xcd * ncm + (j % ncm);
    tn = j / ncm;
  } else {
    tm = (int)blockIdx.x; tn = (int)blockIdx.y;
  }
  const int bm0 = tm * 256, bn0 = tn * 256;

  const int srow = lane >> 3;              // 0..7
  const int sblk = (lane & 7) ^ srow;      // swizzled source 16B block
  const int NT = K >> 6;

  const ushort* Astg = A + (size_t)(bm0 + wave * 8 + srow) * K + sblk * 8;
  const ushort* Bstg = Bt + (size_t)(bn0 + wave * 8 + srow) * K + sblk * 8;

#define SA(i, kt, base)                                                        \
  GLD16(Astg + (size_t)((i) * 64) * K + (kt) * 64,                             \
        &sm[(base) + (i) * 4096 + wave * 512])
#define SB(i, kt, base)                                                        \
  GLD16(Bstg + (size_t)((i) * 64) * K + (kt) * 64,                             \
        &sm[(base) + 16384 + (i) * 4096 + wave * 512])

  const int rsw = l16 & 7;
  const int c80 = (quad ^ rsw) << 3;         // kh=0 block offset (ushort)
  const int c81 = ((4 + quad) ^ rsw) << 3;   // kh=1
  const int aoff = (wm * 128 + l16) * 64;
  const int boff = 16384 + (wn * 64 + l16) * 64;

  f32x4 acc[8][4];
#pragma unroll
  for (int i = 0; i < 8; i++)
#pragma unroll
    for (int j = 0; j < 4; j++) acc[i][j] = (f32x4){0.f, 0.f, 0.f, 0.f};

  // ---- prologue: stage tile0 and tile1 fully ----
#pragma unroll
  for (int i = 0; i < 4; i++) { SA(i, 0, 0); SB(i, 0, 0); }
  if (NT > 1) {
#pragma unroll
    for (int i = 0; i < 4; i++) { SA(i, 1, 32768); SB(i, 1, 32768); }
    asm volatile("s_waitcnt vmcnt(8)" ::: "memory");
  } else {
    asm volatile("s_waitcnt vmcnt(0)" ::: "memory");
  }
  __builtin_amdgcn_s_barrier();

  bf16x8 af[4][2], b01[2][2], b23[2][2];

  for (int t = 0; t < NT; ++t) {
    const int cb = (t & 1) << 15;   // current buffer base (ushort idx)
    // ===== P0: read a0-3 + b0-1 | MFMA r0-3 x c0-1 =====
#pragma unroll
    for (int i = 0; i < 4; i++) {
      af[i][0] = *(const bf16x8*)&sm[cb + aoff + i * 1024 + c80];
      af[i][1] = *(const bf16x8*)&sm[cb + aoff + i * 1024 + c81];
    }
#pragma unroll
    for (int j = 0; j < 2; j++) {
      b01[j][0] = *(const bf16x8*)&sm[cb + boff + j * 1024 + c80];
      b01[j][1] = *(const bf16x8*)&sm[cb + boff + j * 1024 + c81];
    }
    __builtin_amdgcn_s_barrier();
    asm volatile("s_waitcnt lgkmcnt(0)" ::: "memory");
    __builtin_amdgcn_sched_barrier(0);
    __builtin_amdgcn_s_setprio(1);
#pragma unroll
    for (int i = 0; i < 4; i++)
#pragma unroll
      for (int j = 0; j < 2; j++) {
        acc[i][j] = __builtin_amdgcn_mfma_f32_16x16x32_bf16(
            b01[j][0], af[i][0], acc[i][j], 0, 0, 0);
        acc[i][j] = __builtin_amdgcn_mfma_f32_16x16x32_bf16(
            b01[j][1], af[i][1], acc[i][j], 0, 0, 0);
      }
    __builtin_amdgcn_s_setprio(0);
    __builtin_amdgcn_s_barrier();
    // ===== P1: read b2-3 | MFMA r0-3 x c2-3 =====
#pragma unroll
    for (int j = 0; j < 2; j++) {
      b23[j][0] = *(const bf16x8*)&sm[cb + boff + (2 + j) * 1024 + c80];
      b23[j][1] = *(const bf16x8*)&sm[cb + boff + (2 + j) * 1024 + c81];
    }
    __builtin_amdgcn_s_barrier();
    asm volatile("s_waitcnt lgkmcnt(0)" ::: "memory");
    __builtin_amdgcn_sched_barrier(0);
    __builtin_amdgcn_s_setprio(1);
#pragma unroll
    for (int i = 0; i < 4; i++)
#pragma unroll
      for (int j = 0; j < 2; j++) {
        acc[i][2 + j] = __builtin_amdgcn_mfma_f32_16x16x32_bf16(
            b23[j][0], af[i][0], acc[i][2 + j], 0, 0, 0);
        acc[i][2 + j] = __builtin_amdgcn_mfma_f32_16x16x32_bf16(
            b23[j][1], af[i][1], acc[i][2 + j], 0, 0, 0);
      }
    __builtin_amdgcn_s_setprio(0);
    __builtin_amdgcn_s_barrier();
    // ===== P2: read a4-7 | MFMA r4-7 x c0-1 =====
#pragma unroll
    for (int i = 0; i < 4; i++) {
      af[i][0] = *(const bf16x8*)&sm[cb + aoff + (4 + i) * 1024 + c80];
      af[i][1] = *(const bf16x8*)&sm[cb + aoff + (4 + i) * 1024 + c81];
    }
    __builtin_amdgcn_s_barrier();
    asm volatile("s_waitcnt lgkmcnt(0)" ::: "memory");
    __builtin_amdgcn_sched_barrier(0);
    __builtin_amdgcn_s_setprio(1);
#pragma unroll
    for (int i = 0; i < 4; i++)
#pragma unroll
      for (int j = 0; j < 2; j++) {
        acc[4 + i][j] = __builtin_amdgcn_mfma_f32_16x16x32_bf16(
            b01[j][0], af[i][0], acc[4 + i][j], 0, 0, 0);
        acc[4 + i][j] = __builtin_amdgcn_mfma_f32_16x16x32_bf16(
            b01[j][1], af[i][1], acc[4 + i][j], 0, 0, 0);
      }
    __builtin_amdgcn_s_setprio(0);
    __builtin_amdgcn_s_barrier();
    // ===== P3: stage ALL of tile t+2 into cb | MFMA r4-7 x c2-3 | vmcnt ====
    if (t + 2 < NT) {
#pragma unroll
      for (int i = 0; i < 4; i++) { SA(i, t + 2, cb); SB(i, t + 2, cb); }
    }
    __builtin_amdgcn_s_setprio(1);
#pragma unroll
    for (int i = 0; i < 4; i++)
#pragma unroll
      for (int j = 0; j < 2; j++) {
        acc[4 + i][2 + j] = __builtin_amdgcn_mfma_f32_16x16x32_bf16(
            b23[j][0], af[i][0], acc[4 + i][2 + j], 0, 0, 0);
        acc[4 + i][2 + j] = __builtin_amdgcn_mfma_f32_16x16x32_bf16(
            b23[j][1], af[i][1], acc[4 + i][2 + j], 0, 0, 0);
      }
    __builtin_amdgcn_s_setprio(0);
    if (t + 2 < NT) {
      asm volatile("s_waitcnt vmcnt(8)" ::: "memory");
    } else {
      asm volatile("s_waitcnt vmcnt(0)" ::: "memory");
    }
    __builtin_amdgcn_s_barrier();
  }
#undef SA
#undef SB

  // ---- epilogue: lane owns row l16, 4 consecutive cols per fragment ----
#pragma unroll
  for (int i = 0; i < 8; i++) {
    const size_t row = (size_t)(bm0 + wm * 128 + i * 16 + l16);
#pragma unroll
    for (int j = 0; j < 4; j++) {
      const int c = bn0 + wn * 64 + j * 16 + quad * 4;
      const float4 bv = *(const float4*)(bias + c);
      const float v0 = acc[i][j][0] + bv.x;
      const float v1 = acc[i][j][1] + bv.y;
      const float v2 = acc[i][j][2] + bv.z;
      const float v3 = acc[i][j][3] + bv.w;
      if (EPI == 0) {
        ushort4 o;
        if (c < 1024) {
          o.x = f2bf(v0 / (1.f + __expf(-v0)));
          o.y = f2bf(v1 / (1.f + __expf(-v1)));
          o.z = f2bf(v2 / (1.f + __expf(-v2)));
          o.w = f2bf(v3 / (1.f + __expf(-v3)));
          *(ushort4*)((ushort*)p0 + row * 1024 + c) = o;
        } else {
          o.x = f2bf(1.f / (1.f + __expf(-v0)));
          o.y = f2bf(1.f / (1.f + __expf(-v1)));
          o.z = f2bf(1.f / (1.f + __expf(-v2)));
          o.w = f2bf(1.f / (1.f + __expf(-v3)));
          *(ushort4*)((ushort*)p1 + row * 1024 + (c - 1024)) = o;
        }
      } else if (EPI == 1) {
        float4* io = (float4*)((float*)p0 + row * 1024 + c);
        float4 t4 = *io;
        t4.x += v0; t4.y += v1; t4.z += v2; t4.w += v3;
        *io = t4;
      } else if (EPI == 2) {
        ushort4 o;
        o.x = f2bf(0.5f * v0 * (1.f + erff(v0 * 0.70710678118654752f)));
        o.y = f2bf(0.5f * v1 * (1.f + erff(v1 * 0.70710678118654752f)));
        o.z = f2bf(0.5f * v2 * (1.f + erff(v2 * 0.70710678118654752f)));
        o.w = f2bf(0.5f * v3 * (1.f + erff(v3 * 0.70710678118654752f)));
        *(ushort4*)((ushort*)p0 + row * 2048 + c) = o;
      } else {
        const float4 pv = *(const float4*)((const float*)p1 + row * 1024 + c);
        float4 t4;
        t4.x = pv.x + v0; t4.y = pv.y + v1;
        t4.z = pv.z + v2; t4.w = pv.w + v3;
        *(float4*)((float*)p0 + row * 1024 + c) = t4;
      }
    }
  }
}

// ---------------------------------------------------------------------------
extern "C" void kernel_launch(void* const* d_in, const int* in_sizes, int n_in,
                              void* d_out, int out_size, void* d_ws,
                              size_t ws_size, hipStream_t stream) {
  const float* x      = (const float*)d_in[0];
  const float* ln1_w  = (const float*)d_in[1];
  const float* ln1_b  = (const float*)d_in[2];
  const float* conv_w = (const float*)d_in[3];
  const float* conv_b = (const float*)d_in[4];
  const float* lns_w  = (const float*)d_in[5];
  const float* lns_b  = (const float*)d_in[6];
  const float* in_w   = (const float*)d_in[7];
  const float* in_b   = (const float*)d_in[8];
  const float* xp_w   = (const float*)d_in[9];
  const float* xp_b   = (const float*)d_in[10];
  const float* A_log  = (const float*)d_in[11];
  const float* Dm     = (const float*)d_in[12];
  const float* out_w  = (const float*)d_in[13];
  const float* out_b  = (const float*)d_in[14];
  const float* ln2_w  = (const float*)d_in[15];
  const float* ln2_b  = (const float*)d_in[16];
  const float* mlp_w1 = (const float*)d_in[17];
  const float* mlp_b1 = (const float*)d_in[18];
  const float* mlp_w2 = (const float*)d_in[19];
  const float* mlp_b2 = (const float*)d_in[20];

  char* wsp = (char*)d_ws;
  size_t off = 0;
  auto alloc = [&](size_t bytes) {
    void* p = wsp + off;
    off += (bytes + 255) & ~(size_t)255;
    return p;
  };
  // 16384 rows x 1024. Aliasing plan (lifetimes disjoint):
  float*  x1    = (float*)alloc(67108864);   // x1 -> x2 (in-place residual)
  ushort* abuf  = (ushort*)alloc(67108864);  // lnS out (dead after GEMM1)
  ushort* gbuf  = abuf + 16777216;           // g (written after GEMM1)
  ushort* xpb   = (ushort*)alloc(33554432);  // xp; later h (ln2 out)
  ushort* zb    = (ushort*)alloc(67108864);  // z bf16 (32MB); later h1 bf16
  ushort* h1b   = (ushort*)zb;
  float*  ub    = (float*)alloc(1048576);
  float*  hsb   = (float*)alloc(1048576);
  float2* stb   = (float2*)alloc(131072);    // 16384 x (mean, rstd)
  ushort* in_wT = (ushort*)alloc(4194304);   // 2048 x 1024
  ushort* out_wT= (ushort*)alloc(2097152);   // 1024 x 1024
  ushort* w1T   = (ushort*)alloc(4194304);   // 2048 x 1024
  ushort* w2T   = (ushort*)alloc(4194304);   // 1024 x 2048

  wt_all_kernel<<<7168, 256, 0, stream>>>(in_w, out_w, mlp_w1, mlp_w2,
                                          in_wT, out_wT, w1T, w2T);
  rowstats_kernel<<<4096, 256, 0, stream>>>(x, stb);
  lnconv_kernel<<<4096, 256, 0, stream>>>(x, stb, ln1_w, ln1_b, conv_w,
                                          conv_b, lns_w, lns_b, x1, abuf);
  gemm_bt<0><<<dim3(64, 8), 512, 0, stream>>>(abuf, in_wT, in_b, 1024,
                                              xpb, zb);
  u_mfma_kernel<<<256, 256, 0, stream>>>(xpb, xp_w, xp_b, ub);
  scan_kernel<<<64, 256, 0, stream>>>(ub, A_log, hsb);
  g_kernel<<<1024, 256, 0, stream>>>(hsb, Dm, zb, gbuf);
  gemm_bt<1><<<dim3(64, 4), 512, 0, stream>>>(gbuf, out_wT, out_b, 1024,
                                              x1, nullptr);
  ln_kernel<1><<<4096, 256, 0, stream>>>(x1, ln2_w, ln2_b, xpb);
  gemm_bt<2><<<dim3(64, 8), 512, 0, stream>>>(xpb, w1T, mlp_b1, 1024,
                                              h1b, nullptr);
  gemm_bt<3><<<dim3(64, 4), 512, 0, stream>>>(h1b, w2T, mlp_b2, 2048,
                                              d_out, x1);
}

// Round 5
// 628.376 us; speedup vs baseline: 1.0159x; 1.0159x over previous
//
#include <hip/hip_runtime.h>
#include <cstdint>
#include <cstddef>

// ---------------------------------------------------------------------------
// MambaBlock fused pipeline for MI355X (gfx950).
// B=4, S=4096, d=1024, n=16. M = 16384 token rows.
// R5: gemm_bt K-loop collapsed to TWO barriers per K-tile (was 8):
//     {24 ds_read + 64 MFMA (compiler-scheduled) ; lgkmcnt(0) ; barrier ;
//      stage tile t+2 (8x GLD16) ; vmcnt(8) ; barrier}.
//     Depth-2 pipeline retained. No setprio (m190: hurts lockstep), no
//     sched_barrier pinning. Raw s_barrier + explicit memory-clobber asm.
//     Epilogue/raster/front-end identical to R4.
// ---------------------------------------------------------------------------

typedef short bf16x8 __attribute__((ext_vector_type(8)));
typedef float f32x4 __attribute__((ext_vector_type(4)));

#define GLD16(gp, lp)                                                          \
  __builtin_amdgcn_global_load_lds(                                            \
      (__attribute__((address_space(1))) void*)(gp),                           \
      (__attribute__((address_space(3))) void*)(lp), 16, 0, 0)

static __device__ __forceinline__ ushort f2bf(float f) {
  union { float f; uint32_t u; } c; c.f = f;
  uint32_t r = c.u + 0x7FFFu + ((c.u >> 16) & 1u);
  return (ushort)(r >> 16);
}
static __device__ __forceinline__ float bf2f(ushort u) {
  union { uint32_t u; float f; } c; c.u = ((uint32_t)u) << 16;
  return c.f;
}

// ---------- per-row LN stats: one wave per 1024-wide row -------------------
__global__ __launch_bounds__(256) void rowstats_kernel(
    const float* __restrict__ x, float2* __restrict__ stats) {
  const int row = blockIdx.x * 4 + (threadIdx.x >> 6);
  const int lane = threadIdx.x & 63;
  const float4* xr = (const float4*)(x + (size_t)row * 1024);
  float s = 0.f, q = 0.f;
#pragma unroll
  for (int i = 0; i < 4; i++) {
    const float4 v = xr[lane + i * 64];
    s += v.x + v.y + v.z + v.w;
    q += v.x * v.x + v.y * v.y + v.z * v.z + v.w * v.w;
  }
#pragma unroll
  for (int off = 32; off > 0; off >>= 1) {
    s += __shfl_down(s, off);
    q += __shfl_down(q, off);
  }
  if (lane == 0) {
    const float mean = s * (1.f / 1024.f);
    const float var  = q * (1.f / 1024.f) - mean * mean;
    stats[row] = make_float2(mean, rsqrtf(var + 1e-5f));
  }
}

// ---- fused conv front-end, wave-per-row: ln1 via stats -> depthwise -------
// ---- conv(k=4) + residual -> x1; then lnS(x1) -> abuf (bf16). -------------
__global__ __launch_bounds__(256) void lnconv_kernel(
    const float* __restrict__ x, const float2* __restrict__ stats,
    const float* __restrict__ ln1w, const float* __restrict__ ln1b,
    const float* __restrict__ cw, const float* __restrict__ cb,
    const float* __restrict__ lnsw, const float* __restrict__ lnsb,
    float* __restrict__ x1, ushort* __restrict__ abuf) {
  const int row = blockIdx.x * 4 + (threadIdx.x >> 6);  // b*4096 + t
  const int t = row & 4095;
  const int lane = threadIdx.x & 63;
  const float4* x4 = (const float4*)x;

  float2 st[4];
#pragma unroll
  for (int j = 0; j < 4; j++)
    st[j] = (t - 3 + j >= 0) ? stats[row - 3 + j] : make_float2(0.f, 0.f);

  float4 o[4];
  float s = 0.f, q = 0.f;
#pragma unroll
  for (int i = 0; i < 4; i++) {
    const int f4 = lane + i * 64;   // float4 index within row
    const int c0 = f4 * 4;          // channel base
    float4 acc = *(const float4*)(cb + c0);
    const float4 w0 = *(const float4*)(cw + (size_t)(c0 + 0) * 4);
    const float4 w1 = *(const float4*)(cw + (size_t)(c0 + 1) * 4);
    const float4 w2 = *(const float4*)(cw + (size_t)(c0 + 2) * 4);
    const float4 w3 = *(const float4*)(cw + (size_t)(c0 + 3) * 4);
    const float4 wv4 = ((const float4*)ln1w)[f4];
    const float4 bv4 = ((const float4*)ln1b)[f4];
    float4 xm = make_float4(0.f, 0.f, 0.f, 0.f);
#pragma unroll
    for (int j = 0; j < 4; j++) {
      if (t - 3 + j >= 0) {
        const float4 xv = x4[(size_t)(row - 3 + j) * 256 + f4];
        if (j == 3) xm = xv;
        const float mean = st[j].x, rstd = st[j].y;
        const float lx = (xv.x - mean) * rstd * wv4.x + bv4.x;
        const float ly = (xv.y - mean) * rstd * wv4.y + bv4.y;
        const float lz = (xv.z - mean) * rstd * wv4.z + bv4.z;
        const float lw = (xv.w - mean) * rstd * wv4.w + bv4.w;
        acc.x += lx * ((const float*)&w0)[j];
        acc.y += ly * ((const float*)&w1)[j];
        acc.z += lz * ((const float*)&w2)[j];
        acc.w += lw * ((const float*)&w3)[j];
      }
    }
    o[i].x = xm.x + acc.x; o[i].y = xm.y + acc.y;
    o[i].z = xm.z + acc.z; o[i].w = xm.w + acc.w;
    ((float4*)x1)[(size_t)row * 256 + f4] = o[i];
    s += o[i].x + o[i].y + o[i].z + o[i].w;
    q += o[i].x * o[i].x + o[i].y * o[i].y + o[i].z * o[i].z + o[i].w * o[i].w;
  }
  // ---- lnS butterfly reduce (all lanes get total) ----
#pragma unroll
  for (int off = 1; off < 64; off <<= 1) {
    s += __shfl_xor(s, off);
    q += __shfl_xor(q, off);
  }
  const float mean = s * (1.f / 1024.f);
  const float var  = q * (1.f / 1024.f) - mean * mean;
  const float rstd = rsqrtf(var + 1e-5f);
#pragma unroll
  for (int i = 0; i < 4; i++) {
    const int f4 = lane + i * 64;
    const float4 wv4 = ((const float4*)lnsw)[f4];
    const float4 bv4 = ((const float4*)lnsb)[f4];
    ushort4 a;
    a.x = f2bf((o[i].x - mean) * rstd * wv4.x + bv4.x);
    a.y = f2bf((o[i].y - mean) * rstd * wv4.y + bv4.y);
    a.z = f2bf((o[i].z - mean) * rstd * wv4.z + bv4.z);
    a.w = f2bf((o[i].w - mean) * rstd * wv4.w + bv4.w);
    ((ushort4*)(abuf + (size_t)row * 1024))[f4] = a;
  }
}

// ---------------- LayerNorm: one wave per 1024-wide row --------------------
template <int BF16OUT>
__global__ __launch_bounds__(256) void ln_kernel(
    const float* __restrict__ x, const float* __restrict__ w,
    const float* __restrict__ b, void* __restrict__ out) {
  const int row = blockIdx.x * 4 + (threadIdx.x >> 6);
  const int lane = threadIdx.x & 63;
  const float4* xr = (const float4*)(x + (size_t)row * 1024);
  float4 v[4];
  float s = 0.f, q = 0.f;
#pragma unroll
  for (int i = 0; i < 4; i++) {
    v[i] = xr[lane + i * 64];
    s += v[i].x + v[i].y + v[i].z + v[i].w;
    q += v[i].x * v[i].x + v[i].y * v[i].y + v[i].z * v[i].z + v[i].w * v[i].w;
  }
#pragma unroll
  for (int off = 1; off < 64; off <<= 1) {
    s += __shfl_xor(s, off);
    q += __shfl_xor(q, off);
  }
  const float mean = s * (1.f / 1024.f);
  const float var  = q * (1.f / 1024.f) - mean * mean;
  const float rstd = rsqrtf(var + 1e-5f);
#pragma unroll
  for (int i = 0; i < 4; i++) {
    const int f4 = lane + i * 64;
    const float4 wv4 = ((const float4*)w)[f4];
    const float4 bv4 = ((const float4*)b)[f4];
    const float o0 = (v[i].x - mean) * rstd * wv4.x + bv4.x;
    const float o1 = (v[i].y - mean) * rstd * wv4.y + bv4.y;
    const float o2 = (v[i].z - mean) * rstd * wv4.z + bv4.z;
    const float o3 = (v[i].w - mean) * rstd * wv4.w + bv4.w;
    if (BF16OUT) {
      ushort4 o; o.x = f2bf(o0); o.y = f2bf(o1); o.z = f2bf(o2); o.w = f2bf(o3);
      ((ushort4*)((ushort*)out + (size_t)row * 1024))[f4] = o;
    } else {
      float4 o; o.x = o0; o.y = o1; o.z = o2; o.w = o3;
      ((float4*)((float*)out + (size_t)row * 1024))[f4] = o;
    }
  }
}

// ------- merged tiled transpose + fp32->bf16 for all 4 weights -------------
__global__ __launch_bounds__(256) void wt_all_kernel(
    const float* __restrict__ in_w, const float* __restrict__ out_w,
    const float* __restrict__ w1, const float* __restrict__ w2,
    ushort* __restrict__ in_wT, ushort* __restrict__ out_wT,
    ushort* __restrict__ w1T, ushort* __restrict__ w2T) {
  __shared__ float tile[32][33];
  const int idx = blockIdx.x;
  const float* src; ushort* dst; int K, N, n0, k0;
  if (idx < 2048) {
    src = in_w; dst = in_wT; K = 1024; N = 2048;
    n0 = (idx & 63) * 32; k0 = (idx >> 6) * 32;
  } else if (idx < 3072) {
    const int r = idx - 2048;
    src = out_w; dst = out_wT; K = 1024; N = 1024;
    n0 = (r & 31) * 32; k0 = (r >> 5) * 32;
  } else if (idx < 5120) {
    const int r = idx - 3072;
    src = w1; dst = w1T; K = 1024; N = 2048;
    n0 = (r & 63) * 32; k0 = (r >> 6) * 32;
  } else {
    const int r = idx - 5120;
    src = w2; dst = w2T; K = 2048; N = 1024;
    n0 = (r & 31) * 32; k0 = (r >> 5) * 32;
  }
  const int tx = threadIdx.x & 31, ty = threadIdx.x >> 5;
#pragma unroll
  for (int j = 0; j < 32; j += 8)
    tile[ty + j][tx] = src[(size_t)(k0 + ty + j) * N + n0 + tx];
  __syncthreads();
#pragma unroll
  for (int j = 0; j < 32; j += 8)
    dst[(size_t)(n0 + ty + j) * K + k0 + tx] = f2bf(tile[tx][ty + j]);
}

// ------------- u = xp @ xp_w + xp_b via MFMA (N=16) ------------------------
__global__ __launch_bounds__(256) void u_mfma_kernel(
    const ushort* __restrict__ xp, const float* __restrict__ xpw,
    const float* __restrict__ xpb, float* __restrict__ u) {
  __shared__ ushort Ws[16 * 1024];  // W^T bf16, 16B-block swizzled
  __shared__ ushort As[64 * 64];
  const int tid = threadIdx.x;
  const int wave = tid >> 6, lane = tid & 63;
  const int l16 = lane & 15, quad = lane >> 4;
  for (int e = tid; e < 16384; e += 256) {
    const int n = e & 15, k = e >> 4;
    Ws[n * 1024 + (((k >> 3) ^ (n & 7)) << 3) + (k & 7)] =
        f2bf(xpw[(size_t)k * 16 + n]);
  }
  const int bm0 = blockIdx.x * 64;
  const int srow = lane >> 3, sblk = (lane & 7) ^ (srow & 7);
  const ushort* Ag = xp + (size_t)(bm0 + wave * 16 + srow) * 1024 + sblk * 8;
  ushort* Al = &As[wave * 16 * 64];
  const int rsw = l16 & 7;
  f32x4 acc = (f32x4){0.f, 0.f, 0.f, 0.f};
  __syncthreads();
  for (int k0 = 0; k0 < 1024; k0 += 64) {
    GLD16(Ag + k0, Al);
    GLD16(Ag + k0 + (size_t)8 * 1024, Al + 512);
    __syncthreads();
#pragma unroll
    for (int kh = 0; kh < 2; kh++) {
      const bf16x8 aF = *(const bf16x8*)
          &As[(wave * 16 + l16) * 64 + (((kh * 4 + quad) ^ rsw) << 3)];
      const bf16x8 bF = *(const bf16x8*)
          &Ws[l16 * 1024 + ((((k0 >> 3) + kh * 4 + quad) ^ rsw) << 3)];
      acc = __builtin_amdgcn_mfma_f32_16x16x32_bf16(aF, bF, acc, 0, 0, 0);
    }
    __syncthreads();
  }
  const float bv = xpb[l16];
#pragma unroll
  for (int r = 0; r < 4; r++) {
    const int row = bm0 + wave * 16 + quad * 4 + r;
    u[(size_t)row * 16 + l16] = acc[r] + bv;
  }
}

// ------------- selective scan: one block per (b,n) sequence ----------------
__global__ __launch_bounds__(256) void scan_kernel(
    const float* __restrict__ u, const float* __restrict__ A_log,
    float* __restrict__ hs) {
  const int tid = threadIdx.x;
  const int b = blockIdx.x >> 4;
  const int n = blockIdx.x & 15;
  const float d = expf(-expf(A_log[n]));
  const int t0 = tid * 16;
  const float* up = u + ((size_t)b * 4096) * 16 + n;
  float loc[16];
  float h = 0.f;
#pragma unroll
  for (int i = 0; i < 16; i++) {
    h = d * h + up[(size_t)(t0 + i) * 16];
    loc[i] = h;
  }
  __shared__ float sv[256];
  sv[tid] = h;
  __syncthreads();
  float d16 = d * d; d16 *= d16; d16 *= d16; d16 *= d16;  // d^16
  float f = d16;
  for (int off = 1; off < 256; off <<= 1) {
    const float add = (tid >= off) ? sv[tid - off] : 0.f;
    __syncthreads();
    sv[tid] += f * add;
    __syncthreads();
    f *= f;
  }
  const float carry = (tid > 0) ? sv[tid - 1] : 0.f;
  float dp = d;
#pragma unroll
  for (int i = 0; i < 16; i++) {
    const float hg = loc[i] + dp * carry;
    dp *= d;
    // hs layout: (t*4 + b)*16 + n  == GEMM3 row order m' = t*B + b
    hs[((size_t)(t0 + i) * 4 + b) * 16 + n] = hg;
  }
}

// ------------- g[m'] = (hs[m'] @ D) * z[b,t]  -> bf16 ----------------------
__global__ __launch_bounds__(256) void g_kernel(
    const float* __restrict__ hs, const float* __restrict__ Dm,
    const ushort* __restrict__ z, ushort* __restrict__ g) {
  __shared__ float hsh[256];
  const int tid = threadIdx.x;
  const int r0 = blockIdx.x * 16;
  hsh[tid] = hs[(size_t)r0 * 16 + tid];
  __syncthreads();
  float4 acc[16];
#pragma unroll
  for (int rr = 0; rr < 16; rr++) acc[rr] = make_float4(0.f, 0.f, 0.f, 0.f);
  const float4* Dv = (const float4*)Dm;
#pragma unroll
  for (int n = 0; n < 16; n++) {
    const float4 dv = Dv[(size_t)n * 256 + tid];
#pragma unroll
    for (int rr = 0; rr < 16; rr++) {
      const float h = hsh[rr * 16 + n];
      acc[rr].x += h * dv.x; acc[rr].y += h * dv.y;
      acc[rr].z += h * dv.z; acc[rr].w += h * dv.w;
    }
  }
#pragma unroll
  for (int rr = 0; rr < 16; rr++) {
    const int r = r0 + rr;
    const int b = r & 3, t = r >> 2;
    const ushort4 zv =
        *(const ushort4*)(z + ((size_t)b * 4096 + t) * 1024 + tid * 4);
    ushort4 o;
    o.x = f2bf(acc[rr].x * bf2f(zv.x)); o.y = f2bf(acc[rr].y * bf2f(zv.y));
    o.z = f2bf(acc[rr].z * bf2f(zv.z)); o.w = f2bf(acc[rr].w * bf2f(zv.w));
    *(ushort4*)(g + (size_t)r * 1024 + tid * 4) = o;
  }
}

// ------------- bf16 MFMA GEMM: C = A(MxK) @ Bt(NxK)^T + bias, epilogues ----
// 256x256 tile, BK=64, 8 waves (2Mx4N), dbuf 128KiB LDS, depth-2 pipeline.
// TWO barriers per K-tile:
//   {24 ds_read_b128 + 64 MFMA (compiler-scheduled waits); lgkmcnt(0); bar;
//    stage tile t+2 into cb (8x GLD16); vmcnt(8); bar}
// vmcnt(8): only the 8 just-issued t+2 loads may remain -> t+1 fully staged.
// MFMA operands swapped (bF, aF) -> D^T fragments, vector epilogue stores.
// EPI 0: split N=2048 -> silu->xp bf16 (col<1024), sigmoid->z bf16
// EPI 1: in-place flat residual add | EPI 2: gelu->bf16 | EPI 3: p1+v->p0
template <int EPI>
__global__ __launch_bounds__(512, 2) void gemm_bt(
    const ushort* __restrict__ A, const ushort* __restrict__ Bt,
    const float* __restrict__ bias, int K, void* __restrict__ p0,
    void* __restrict__ p1) {
  __shared__ __align__(16) ushort sm[65536];  // [2 bufs][A 16384 | B 16384]
  const int tid = threadIdx.x;
  const int wave = tid >> 6, lane = tid & 63;
  const int l16 = lane & 15, quad = lane >> 4;
  const int wm = wave >> 2, wn = wave & 3;  // 2 x 4 wave grid

  const int nbx = (int)gridDim.x;
  int tm, tn;
  if ((nbx & 7) == 0) {
    const int lid = (int)blockIdx.y * nbx + (int)blockIdx.x;
    const int ncm = nbx >> 3;
    const int xcd = lid & 7;
    const int j = lid >> 3;
    tm = xcd * ncm + (j % ncm);
    tn = j / ncm;
  } else {
    tm = (int)blockIdx.x; tn = (int)blockIdx.y;
  }
  const int bm0 = tm * 256, bn0 = tn * 256;

  const int srow = lane >> 3;              // 0..7
  const int sblk = (lane & 7) ^ srow;      // swizzled source 16B block
  const int NT = K >> 6;

  const ushort* Astg = A + (size_t)(bm0 + wave * 8 + srow) * K + sblk * 8;
  const ushort* Bstg = Bt + (size_t)(bn0 + wave * 8 + srow) * K + sblk * 8;

#define SA(i, kt, base)                                                        \
  GLD16(Astg + (size_t)((i) * 64) * K + (kt) * 64,                             \
        &sm[(base) + (i) * 4096 + wave * 512])
#define SB(i, kt, base)                                                        \
  GLD16(Bstg + (size_t)((i) * 64) * K + (kt) * 64,                             \
        &sm[(base) + 16384 + (i) * 4096 + wave * 512])

  const int rsw = l16 & 7;
  const int c80 = (quad ^ rsw) << 3;         // kh=0 block offset (ushort)
  const int c81 = ((4 + quad) ^ rsw) << 3;   // kh=1
  const int aoff = (wm * 128 + l16) * 64;
  const int boff = 16384 + (wn * 64 + l16) * 64;

  f32x4 acc[8][4];
#pragma unroll
  for (int i = 0; i < 8; i++)
#pragma unroll
    for (int j = 0; j < 4; j++) acc[i][j] = (f32x4){0.f, 0.f, 0.f, 0.f};

  // ---- prologue: stage tile0 and tile1 fully ----
#pragma unroll
  for (int i = 0; i < 4; i++) { SA(i, 0, 0); SB(i, 0, 0); }
  if (NT > 1) {
#pragma unroll
    for (int i = 0; i < 4; i++) { SA(i, 1, 32768); SB(i, 1, 32768); }
    asm volatile("s_waitcnt vmcnt(8)" ::: "memory");
  } else {
    asm volatile("s_waitcnt vmcnt(0)" ::: "memory");
  }
  __builtin_amdgcn_s_barrier();
  asm volatile("" ::: "memory");

  for (int t = 0; t < NT; ++t) {
    const int cb = (t & 1) << 15;   // current buffer base (ushort idx)
    bf16x8 af[4][2], bfr[4][2];
    // ---- fragment reads: B all 4 col-blocks + A rows 0-3 ----
#pragma unroll
    for (int j = 0; j < 4; j++) {
      bfr[j][0] = *(const bf16x8*)&sm[cb + boff + j * 1024 + c80];
      bfr[j][1] = *(const bf16x8*)&sm[cb + boff + j * 1024 + c81];
    }
#pragma unroll
    for (int i = 0; i < 4; i++) {
      af[i][0] = *(const bf16x8*)&sm[cb + aoff + i * 1024 + c80];
      af[i][1] = *(const bf16x8*)&sm[cb + aoff + i * 1024 + c81];
    }
#pragma unroll
    for (int i = 0; i < 4; i++)
#pragma unroll
      for (int j = 0; j < 4; j++) {
        acc[i][j] = __builtin_amdgcn_mfma_f32_16x16x32_bf16(
            bfr[j][0], af[i][0], acc[i][j], 0, 0, 0);
        acc[i][j] = __builtin_amdgcn_mfma_f32_16x16x32_bf16(
            bfr[j][1], af[i][1], acc[i][j], 0, 0, 0);
      }
    // ---- A rows 4-7 (reuse af regs) ----
#pragma unroll
    for (int i = 0; i < 4; i++) {
      af[i][0] = *(const bf16x8*)&sm[cb + aoff + (4 + i) * 1024 + c80];
      af[i][1] = *(const bf16x8*)&sm[cb + aoff + (4 + i) * 1024 + c81];
    }
#pragma unroll
    for (int i = 0; i < 4; i++)
#pragma unroll
      for (int j = 0; j < 4; j++) {
        acc[4 + i][j] = __builtin_amdgcn_mfma_f32_16x16x32_bf16(
            bfr[j][0], af[i][0], acc[4 + i][j], 0, 0, 0);
        acc[4 + i][j] = __builtin_amdgcn_mfma_f32_16x16x32_bf16(
            bfr[j][1], af[i][1], acc[4 + i][j], 0, 0, 0);
      }
    // ---- barrier 1: all waves done reading cb ----
    asm volatile("s_waitcnt lgkmcnt(0)" ::: "memory");
    __builtin_amdgcn_s_barrier();
    asm volatile("" ::: "memory");
    // ---- stage tile t+2 into cb; counted wait; barrier 2 ----
    if (t + 2 < NT) {
#pragma unroll
      for (int i = 0; i < 4; i++) { SA(i, t + 2, cb); SB(i, t + 2, cb); }
      asm volatile("s_waitcnt vmcnt(8)" ::: "memory");
    } else {
      asm volatile("s_waitcnt vmcnt(0)" ::: "memory");
    }
    __builtin_amdgcn_s_barrier();
    asm volatile("" ::: "memory");
  }
#undef SA
#undef SB

  // ---- epilogue: lane owns row l16, 4 consecutive cols per fragment ----
#pragma unroll
  for (int i = 0; i < 8; i++) {
    const size_t row = (size_t)(bm0 + wm * 128 + i * 16 + l16);
#pragma unroll
    for (int j = 0; j < 4; j++) {
      const int c = bn0 + wn * 64 + j * 16 + quad * 4;
      const float4 bv = *(const float4*)(bias + c);
      const float v0 = acc[i][j][0] + bv.x;
      const float v1 = acc[i][j][1] + bv.y;
      const float v2 = acc[i][j][2] + bv.z;
      const float v3 = acc[i][j][3] + bv.w;
      if (EPI == 0) {
        ushort4 o;
        if (c < 1024) {
          o.x = f2bf(v0 / (1.f + __expf(-v0)));
          o.y = f2bf(v1 / (1.f + __expf(-v1)));
          o.z = f2bf(v2 / (1.f + __expf(-v2)));
          o.w = f2bf(v3 / (1.f + __expf(-v3)));
          *(ushort4*)((ushort*)p0 + row * 1024 + c) = o;
        } else {
          o.x = f2bf(1.f / (1.f + __expf(-v0)));
          o.y = f2bf(1.f / (1.f + __expf(-v1)));
          o.z = f2bf(1.f / (1.f + __expf(-v2)));
          o.w = f2bf(1.f / (1.f + __expf(-v3)));
          *(ushort4*)((ushort*)p1 + row * 1024 + (c - 1024)) = o;
        }
      } else if (EPI == 1) {
        float4* io = (float4*)((float*)p0 + row * 1024 + c);
        float4 t4 = *io;
        t4.x += v0; t4.y += v1; t4.z += v2; t4.w += v3;
        *io = t4;
      } else if (EPI == 2) {
        ushort4 o;
        o.x = f2bf(0.5f * v0 * (1.f + erff(v0 * 0.70710678118654752f)));
        o.y = f2bf(0.5f * v1 * (1.f + erff(v1 * 0.70710678118654752f)));
        o.z = f2bf(0.5f * v2 * (1.f + erff(v2 * 0.70710678118654752f)));
        o.w = f2bf(0.5f * v3 * (1.f + erff(v3 * 0.70710678118654752f)));
        *(ushort4*)((ushort*)p0 + row * 2048 + c) = o;
      } else {
        const float4 pv = *(const float4*)((const float*)p1 + row * 1024 + c);
        float4 t4;
        t4.x = pv.x + v0; t4.y = pv.y + v1;
        t4.z = pv.z + v2; t4.w = pv.w + v3;
        *(float4*)((float*)p0 + row * 1024 + c) = t4;
      }
    }
  }
}

// ---------------------------------------------------------------------------
extern "C" void kernel_launch(void* const* d_in, const int* in_sizes, int n_in,
                              void* d_out, int out_size, void* d_ws,
                              size_t ws_size, hipStream_t stream) {
  const float* x      = (const float*)d_in[0];
  const float* ln1_w  = (const float*)d_in[1];
  const float* ln1_b  = (const float*)d_in[2];
  const float* conv_w = (const float*)d_in[3];
  const float* conv_b = (const float*)d_in[4];
  const float* lns_w  = (const float*)d_in[5];
  const float* lns_b  = (const float*)d_in[6];
  const float* in_w   = (const float*)d_in[7];
  const float* in_b   = (const float*)d_in[8];
  const float* xp_w   = (const float*)d_in[9];
  const float* xp_b   = (const float*)d_in[10];
  const float* A_log  = (const float*)d_in[11];
  const float* Dm     = (const float*)d_in[12];
  const float* out_w  = (const float*)d_in[13];
  const float* out_b  = (const float*)d_in[14];
  const float* ln2_w  = (const float*)d_in[15];
  const float* ln2_b  = (const float*)d_in[16];
  const float* mlp_w1 = (const float*)d_in[17];
  const float* mlp_b1 = (const float*)d_in[18];
  const float* mlp_w2 = (const float*)d_in[19];
  const float* mlp_b2 = (const float*)d_in[20];

  char* wsp = (char*)d_ws;
  size_t off = 0;
  auto alloc = [&](size_t bytes) {
    void* p = wsp + off;
    off += (bytes + 255) & ~(size_t)255;
    return p;
  };
  // 16384 rows x 1024. Aliasing plan (lifetimes disjoint):
  float*  x1    = (float*)alloc(67108864);   // x1 -> x2 (in-place residual)
  ushort* abuf  = (ushort*)alloc(67108864);  // lnS out (dead after GEMM1)
  ushort* gbuf  = abuf + 16777216;           // g (written after GEMM1)
  ushort* xpb   = (ushort*)alloc(33554432);  // xp; later h (ln2 out)
  ushort* zb    = (ushort*)alloc(67108864);  // z bf16 (32MB); later h1 bf16
  ushort* h1b   = (ushort*)zb;
  float*  ub    = (float*)alloc(1048576);
  float*  hsb   = (float*)alloc(1048576);
  float2* stb   = (float2*)alloc(131072);    // 16384 x (mean, rstd)
  ushort* in_wT = (ushort*)alloc(4194304);   // 2048 x 1024
  ushort* out_wT= (ushort*)alloc(2097152);   // 1024 x 1024
  ushort* w1T   = (ushort*)alloc(4194304);   // 2048 x 1024
  ushort* w2T   = (ushort*)alloc(4194304);   // 1024 x 2048

  wt_all_kernel<<<7168, 256, 0, stream>>>(in_w, out_w, mlp_w1, mlp_w2,
                                          in_wT, out_wT, w1T, w2T);
  rowstats_kernel<<<4096, 256, 0, stream>>>(x, stb);
  lnconv_kernel<<<4096, 256, 0, stream>>>(x, stb, ln1_w, ln1_b, conv_w,
                                          conv_b, lns_w, lns_b, x1, abuf);
  gemm_bt<0><<<dim3(64, 8), 512, 0, stream>>>(abuf, in_wT, in_b, 1024,
                                              xpb, zb);
  u_mfma_kernel<<<256, 256, 0, stream>>>(xpb, xp_w, xp_b, ub);
  scan_kernel<<<64, 256, 0, stream>>>(ub, A_log, hsb);
  g_kernel<<<1024, 256, 0, stream>>>(hsb, Dm, zb, gbuf);
  gemm_bt<1><<<dim3(64, 4), 512, 0, stream>>>(gbuf, out_wT, out_b, 1024,
                                              x1, nullptr);
  ln_kernel<1><<<4096, 256, 0, stream>>>(x1, ln2_w, ln2_b, xpb);
  gemm_bt<2><<<dim3(64, 8), 512, 0, stream>>>(xpb, w1T, mlp_b1, 1024,
                                              h1b, nullptr);
  gemm_bt<3><<<dim3(64, 4), 512, 0, stream>>>(h1b, w2T, mlp_b2, 2048,
                                              d_out, x1);
}

// Round 6
// 614.511 us; speedup vs baseline: 1.0388x; 1.0226x over previous
//
#include <hip/hip_runtime.h>
#include <cstdint>
#include <cstddef>

// ---------------------------------------------------------------------------
// MambaBlock fused pipeline for MI355X (gfx950).
// B=4, S=4096, d=1024, n=16. M = 16384 token rows.
// R6: GEMM occupancy experiment. Same two-barrier K-loop as R5, but tile
//     shrunk to 128x128 (8 waves, wave-tile 64x32, acc[4][2]=32 AGPR),
//     BK=64, 64KiB dbuf LDS, __launch_bounds__(512,4) -> 2 blocks/CU,
//     4 waves/SIMD (2x the TLP of R2-R5). Depth-2 pipeline, boundary
//     vmcnt(4). Discriminates latency-TLP vs LDS-BW vs staging-path walls.
// Front-end identical to R5.
// ---------------------------------------------------------------------------

typedef short bf16x8 __attribute__((ext_vector_type(8)));
typedef float f32x4 __attribute__((ext_vector_type(4)));

#define GLD16(gp, lp)                                                          \
  __builtin_amdgcn_global_load_lds(                                            \
      (__attribute__((address_space(1))) void*)(gp),                           \
      (__attribute__((address_space(3))) void*)(lp), 16, 0, 0)

static __device__ __forceinline__ ushort f2bf(float f) {
  union { float f; uint32_t u; } c; c.f = f;
  uint32_t r = c.u + 0x7FFFu + ((c.u >> 16) & 1u);
  return (ushort)(r >> 16);
}
static __device__ __forceinline__ float bf2f(ushort u) {
  union { uint32_t u; float f; } c; c.u = ((uint32_t)u) << 16;
  return c.f;
}

// ---------- per-row LN stats: one wave per 1024-wide row -------------------
__global__ __launch_bounds__(256) void rowstats_kernel(
    const float* __restrict__ x, float2* __restrict__ stats) {
  const int row = blockIdx.x * 4 + (threadIdx.x >> 6);
  const int lane = threadIdx.x & 63;
  const float4* xr = (const float4*)(x + (size_t)row * 1024);
  float s = 0.f, q = 0.f;
#pragma unroll
  for (int i = 0; i < 4; i++) {
    const float4 v = xr[lane + i * 64];
    s += v.x + v.y + v.z + v.w;
    q += v.x * v.x + v.y * v.y + v.z * v.z + v.w * v.w;
  }
#pragma unroll
  for (int off = 32; off > 0; off >>= 1) {
    s += __shfl_down(s, off);
    q += __shfl_down(q, off);
  }
  if (lane == 0) {
    const float mean = s * (1.f / 1024.f);
    const float var  = q * (1.f / 1024.f) - mean * mean;
    stats[row] = make_float2(mean, rsqrtf(var + 1e-5f));
  }
}

// ---- fused conv front-end, wave-per-row: ln1 via stats -> depthwise -------
// ---- conv(k=4) + residual -> x1; then lnS(x1) -> abuf (bf16). -------------
__global__ __launch_bounds__(256) void lnconv_kernel(
    const float* __restrict__ x, const float2* __restrict__ stats,
    const float* __restrict__ ln1w, const float* __restrict__ ln1b,
    const float* __restrict__ cw, const float* __restrict__ cb,
    const float* __restrict__ lnsw, const float* __restrict__ lnsb,
    float* __restrict__ x1, ushort* __restrict__ abuf) {
  const int row = blockIdx.x * 4 + (threadIdx.x >> 6);  // b*4096 + t
  const int t = row & 4095;
  const int lane = threadIdx.x & 63;
  const float4* x4 = (const float4*)x;

  float2 st[4];
#pragma unroll
  for (int j = 0; j < 4; j++)
    st[j] = (t - 3 + j >= 0) ? stats[row - 3 + j] : make_float2(0.f, 0.f);

  float4 o[4];
  float s = 0.f, q = 0.f;
#pragma unroll
  for (int i = 0; i < 4; i++) {
    const int f4 = lane + i * 64;   // float4 index within row
    const int c0 = f4 * 4;          // channel base
    float4 acc = *(const float4*)(cb + c0);
    const float4 w0 = *(const float4*)(cw + (size_t)(c0 + 0) * 4);
    const float4 w1 = *(const float4*)(cw + (size_t)(c0 + 1) * 4);
    const float4 w2 = *(const float4*)(cw + (size_t)(c0 + 2) * 4);
    const float4 w3 = *(const float4*)(cw + (size_t)(c0 + 3) * 4);
    const float4 wv4 = ((const float4*)ln1w)[f4];
    const float4 bv4 = ((const float4*)ln1b)[f4];
    float4 xm = make_float4(0.f, 0.f, 0.f, 0.f);
#pragma unroll
    for (int j = 0; j < 4; j++) {
      if (t - 3 + j >= 0) {
        const float4 xv = x4[(size_t)(row - 3 + j) * 256 + f4];
        if (j == 3) xm = xv;
        const float mean = st[j].x, rstd = st[j].y;
        const float lx = (xv.x - mean) * rstd * wv4.x + bv4.x;
        const float ly = (xv.y - mean) * rstd * wv4.y + bv4.y;
        const float lz = (xv.z - mean) * rstd * wv4.z + bv4.z;
        const float lw = (xv.w - mean) * rstd * wv4.w + bv4.w;
        acc.x += lx * ((const float*)&w0)[j];
        acc.y += ly * ((const float*)&w1)[j];
        acc.z += lz * ((const float*)&w2)[j];
        acc.w += lw * ((const float*)&w3)[j];
      }
    }
    o[i].x = xm.x + acc.x; o[i].y = xm.y + acc.y;
    o[i].z = xm.z + acc.z; o[i].w = xm.w + acc.w;
    ((float4*)x1)[(size_t)row * 256 + f4] = o[i];
    s += o[i].x + o[i].y + o[i].z + o[i].w;
    q += o[i].x * o[i].x + o[i].y * o[i].y + o[i].z * o[i].z + o[i].w * o[i].w;
  }
  // ---- lnS butterfly reduce (all lanes get total) ----
#pragma unroll
  for (int off = 1; off < 64; off <<= 1) {
    s += __shfl_xor(s, off);
    q += __shfl_xor(q, off);
  }
  const float mean = s * (1.f / 1024.f);
  const float var  = q * (1.f / 1024.f) - mean * mean;
  const float rstd = rsqrtf(var + 1e-5f);
#pragma unroll
  for (int i = 0; i < 4; i++) {
    const int f4 = lane + i * 64;
    const float4 wv4 = ((const float4*)lnsw)[f4];
    const float4 bv4 = ((const float4*)lnsb)[f4];
    ushort4 a;
    a.x = f2bf((o[i].x - mean) * rstd * wv4.x + bv4.x);
    a.y = f2bf((o[i].y - mean) * rstd * wv4.y + bv4.y);
    a.z = f2bf((o[i].z - mean) * rstd * wv4.z + bv4.z);
    a.w = f2bf((o[i].w - mean) * rstd * wv4.w + bv4.w);
    ((ushort4*)(abuf + (size_t)row * 1024))[f4] = a;
  }
}

// ---------------- LayerNorm: one wave per 1024-wide row --------------------
template <int BF16OUT>
__global__ __launch_bounds__(256) void ln_kernel(
    const float* __restrict__ x, const float* __restrict__ w,
    const float* __restrict__ b, void* __restrict__ out) {
  const int row = blockIdx.x * 4 + (threadIdx.x >> 6);
  const int lane = threadIdx.x & 63;
  const float4* xr = (const float4*)(x + (size_t)row * 1024);
  float4 v[4];
  float s = 0.f, q = 0.f;
#pragma unroll
  for (int i = 0; i < 4; i++) {
    v[i] = xr[lane + i * 64];
    s += v[i].x + v[i].y + v[i].z + v[i].w;
    q += v[i].x * v[i].x + v[i].y * v[i].y + v[i].z * v[i].z + v[i].w * v[i].w;
  }
#pragma unroll
  for (int off = 1; off < 64; off <<= 1) {
    s += __shfl_xor(s, off);
    q += __shfl_xor(q, off);
  }
  const float mean = s * (1.f / 1024.f);
  const float var  = q * (1.f / 1024.f) - mean * mean;
  const float rstd = rsqrtf(var + 1e-5f);
#pragma unroll
  for (int i = 0; i < 4; i++) {
    const int f4 = lane + i * 64;
    const float4 wv4 = ((const float4*)w)[f4];
    const float4 bv4 = ((const float4*)b)[f4];
    const float o0 = (v[i].x - mean) * rstd * wv4.x + bv4.x;
    const float o1 = (v[i].y - mean) * rstd * wv4.y + bv4.y;
    const float o2 = (v[i].z - mean) * rstd * wv4.z + bv4.z;
    const float o3 = (v[i].w - mean) * rstd * wv4.w + bv4.w;
    if (BF16OUT) {
      ushort4 o; o.x = f2bf(o0); o.y = f2bf(o1); o.z = f2bf(o2); o.w = f2bf(o3);
      ((ushort4*)((ushort*)out + (size_t)row * 1024))[f4] = o;
    } else {
      float4 o; o.x = o0; o.y = o1; o.z = o2; o.w = o3;
      ((float4*)((float*)out + (size_t)row * 1024))[f4] = o;
    }
  }
}

// ------- merged tiled transpose + fp32->bf16 for all 4 weights -------------
__global__ __launch_bounds__(256) void wt_all_kernel(
    const float* __restrict__ in_w, const float* __restrict__ out_w,
    const float* __restrict__ w1, const float* __restrict__ w2,
    ushort* __restrict__ in_wT, ushort* __restrict__ out_wT,
    ushort* __restrict__ w1T, ushort* __restrict__ w2T) {
  __shared__ float tile[32][33];
  const int idx = blockIdx.x;
  const float* src; ushort* dst; int K, N, n0, k0;
  if (idx < 2048) {
    src = in_w; dst = in_wT; K = 1024; N = 2048;
    n0 = (idx & 63) * 32; k0 = (idx >> 6) * 32;
  } else if (idx < 3072) {
    const int r = idx - 2048;
    src = out_w; dst = out_wT; K = 1024; N = 1024;
    n0 = (r & 31) * 32; k0 = (r >> 5) * 32;
  } else if (idx < 5120) {
    const int r = idx - 3072;
    src = w1; dst = w1T; K = 1024; N = 2048;
    n0 = (r & 63) * 32; k0 = (r >> 6) * 32;
  } else {
    const int r = idx - 5120;
    src = w2; dst = w2T; K = 2048; N = 1024;
    n0 = (r & 31) * 32; k0 = (r >> 5) * 32;
  }
  const int tx = threadIdx.x & 31, ty = threadIdx.x >> 5;
#pragma unroll
  for (int j = 0; j < 32; j += 8)
    tile[ty + j][tx] = src[(size_t)(k0 + ty + j) * N + n0 + tx];
  __syncthreads();
#pragma unroll
  for (int j = 0; j < 32; j += 8)
    dst[(size_t)(n0 + ty + j) * K + k0 + tx] = f2bf(tile[tx][ty + j]);
}

// ------------- u = xp @ xp_w + xp_b via MFMA (N=16) ------------------------
__global__ __launch_bounds__(256) void u_mfma_kernel(
    const ushort* __restrict__ xp, const float* __restrict__ xpw,
    const float* __restrict__ xpb, float* __restrict__ u) {
  __shared__ ushort Ws[16 * 1024];  // W^T bf16, 16B-block swizzled
  __shared__ ushort As[64 * 64];
  const int tid = threadIdx.x;
  const int wave = tid >> 6, lane = tid & 63;
  const int l16 = lane & 15, quad = lane >> 4;
  for (int e = tid; e < 16384; e += 256) {
    const int n = e & 15, k = e >> 4;
    Ws[n * 1024 + (((k >> 3) ^ (n & 7)) << 3) + (k & 7)] =
        f2bf(xpw[(size_t)k * 16 + n]);
  }
  const int bm0 = blockIdx.x * 64;
  const int srow = lane >> 3, sblk = (lane & 7) ^ (srow & 7);
  const ushort* Ag = xp + (size_t)(bm0 + wave * 16 + srow) * 1024 + sblk * 8;
  ushort* Al = &As[wave * 16 * 64];
  const int rsw = l16 & 7;
  f32x4 acc = (f32x4){0.f, 0.f, 0.f, 0.f};
  __syncthreads();
  for (int k0 = 0; k0 < 1024; k0 += 64) {
    GLD16(Ag + k0, Al);
    GLD16(Ag + k0 + (size_t)8 * 1024, Al + 512);
    __syncthreads();
#pragma unroll
    for (int kh = 0; kh < 2; kh++) {
      const bf16x8 aF = *(const bf16x8*)
          &As[(wave * 16 + l16) * 64 + (((kh * 4 + quad) ^ rsw) << 3)];
      const bf16x8 bF = *(const bf16x8*)
          &Ws[l16 * 1024 + ((((k0 >> 3) + kh * 4 + quad) ^ rsw) << 3)];
      acc = __builtin_amdgcn_mfma_f32_16x16x32_bf16(aF, bF, acc, 0, 0, 0);
    }
    __syncthreads();
  }
  const float bv = xpb[l16];
#pragma unroll
  for (int r = 0; r < 4; r++) {
    const int row = bm0 + wave * 16 + quad * 4 + r;
    u[(size_t)row * 16 + l16] = acc[r] + bv;
  }
}

// ------------- selective scan: one block per (b,n) sequence ----------------
__global__ __launch_bounds__(256) void scan_kernel(
    const float* __restrict__ u, const float* __restrict__ A_log,
    float* __restrict__ hs) {
  const int tid = threadIdx.x;
  const int b = blockIdx.x >> 4;
  const int n = blockIdx.x & 15;
  const float d = expf(-expf(A_log[n]));
  const int t0 = tid * 16;
  const float* up = u + ((size_t)b * 4096) * 16 + n;
  float loc[16];
  float h = 0.f;
#pragma unroll
  for (int i = 0; i < 16; i++) {
    h = d * h + up[(size_t)(t0 + i) * 16];
    loc[i] = h;
  }
  __shared__ float sv[256];
  sv[tid] = h;
  __syncthreads();
  float d16 = d * d; d16 *= d16; d16 *= d16; d16 *= d16;  // d^16
  float f = d16;
  for (int off = 1; off < 256; off <<= 1) {
    const float add = (tid >= off) ? sv[tid - off] : 0.f;
    __syncthreads();
    sv[tid] += f * add;
    __syncthreads();
    f *= f;
  }
  const float carry = (tid > 0) ? sv[tid - 1] : 0.f;
  float dp = d;
#pragma unroll
  for (int i = 0; i < 16; i++) {
    const float hg = loc[i] + dp * carry;
    dp *= d;
    // hs layout: (t*4 + b)*16 + n  == GEMM3 row order m' = t*B + b
    hs[((size_t)(t0 + i) * 4 + b) * 16 + n] = hg;
  }
}

// ------------- g[m'] = (hs[m'] @ D) * z[b,t]  -> bf16 ----------------------
__global__ __launch_bounds__(256) void g_kernel(
    const float* __restrict__ hs, const float* __restrict__ Dm,
    const ushort* __restrict__ z, ushort* __restrict__ g) {
  __shared__ float hsh[256];
  const int tid = threadIdx.x;
  const int r0 = blockIdx.x * 16;
  hsh[tid] = hs[(size_t)r0 * 16 + tid];
  __syncthreads();
  float4 acc[16];
#pragma unroll
  for (int rr = 0; rr < 16; rr++) acc[rr] = make_float4(0.f, 0.f, 0.f, 0.f);
  const float4* Dv = (const float4*)Dm;
#pragma unroll
  for (int n = 0; n < 16; n++) {
    const float4 dv = Dv[(size_t)n * 256 + tid];
#pragma unroll
    for (int rr = 0; rr < 16; rr++) {
      const float h = hsh[rr * 16 + n];
      acc[rr].x += h * dv.x; acc[rr].y += h * dv.y;
      acc[rr].z += h * dv.z; acc[rr].w += h * dv.w;
    }
  }
#pragma unroll
  for (int rr = 0; rr < 16; rr++) {
    const int r = r0 + rr;
    const int b = r & 3, t = r >> 2;
    const ushort4 zv =
        *(const ushort4*)(z + ((size_t)b * 4096 + t) * 1024 + tid * 4);
    ushort4 o;
    o.x = f2bf(acc[rr].x * bf2f(zv.x)); o.y = f2bf(acc[rr].y * bf2f(zv.y));
    o.z = f2bf(acc[rr].z * bf2f(zv.z)); o.w = f2bf(acc[rr].w * bf2f(zv.w));
    *(ushort4*)(g + (size_t)r * 1024 + tid * 4) = o;
  }
}

// ------------- bf16 MFMA GEMM: C = A(MxK) @ Bt(NxK)^T + bias, epilogues ----
// 128x128 tile, BK=64, 8 waves (2Mx4N, wave-tile 64x32), 64KiB dbuf LDS,
// 2 blocks/CU (4 waves/SIMD). Two barriers per K-tile, depth-2 pipeline,
// boundary vmcnt(4). MFMA operands swapped -> D^T fragments, vector stores.
// EPI 0: split N=2048 -> silu->xp bf16 (col<1024), sigmoid->z bf16
// EPI 1: in-place flat residual add | EPI 2: gelu->bf16 | EPI 3: p1+v->p0
template <int EPI>
__global__ __launch_bounds__(512, 4) void gemm_bt(
    const ushort* __restrict__ A, const ushort* __restrict__ Bt,
    const float* __restrict__ bias, int K, void* __restrict__ p0,
    void* __restrict__ p1) {
  __shared__ __align__(16) ushort sm[32768];  // [2 bufs][A 8192 | B 8192]
  const int tid = threadIdx.x;
  const int wave = tid >> 6, lane = tid & 63;
  const int l16 = lane & 15, quad = lane >> 4;
  const int wm = wave >> 2, wn = wave & 3;  // 2 x 4 wave grid

  const int nbx = (int)gridDim.x;
  int tm, tn;
  if ((nbx & 7) == 0) {
    const int lid = (int)blockIdx.y * nbx + (int)blockIdx.x;
    const int ncm = nbx >> 3;
    const int xcd = lid & 7;
    const int j = lid >> 3;
    tm = xcd * ncm + (j % ncm);
    tn = j / ncm;
  } else {
    tm = (int)blockIdx.x; tn = (int)blockIdx.y;
  }
  const int bm0 = tm * 128, bn0 = tn * 128;

  const int srow = lane >> 3;              // 0..7
  const int sblk = (lane & 7) ^ srow;      // swizzled source 16B block
  const int NT = K >> 6;

  const ushort* Astg = A + (size_t)(bm0 + wave * 16 + srow) * K + sblk * 8;
  const ushort* Bstg = Bt + (size_t)(bn0 + wave * 16 + srow) * K + sblk * 8;

#define SA(i, kt, base)                                                        \
  GLD16(Astg + (size_t)((i) * 8) * K + (kt) * 64,                              \
        &sm[(base) + (wave * 16 + (i) * 8) * 64])
#define SB(i, kt, base)                                                        \
  GLD16(Bstg + (size_t)((i) * 8) * K + (kt) * 64,                              \
        &sm[(base) + 8192 + (wave * 16 + (i) * 8) * 64])

  const int rsw = l16 & 7;
  const int c80 = (quad ^ rsw) << 3;         // kh=0 block offset (ushort)
  const int c81 = ((4 + quad) ^ rsw) << 3;   // kh=1
  const int aoff = (wm * 64 + l16) * 64;
  const int boff = 8192 + (wn * 32 + l16) * 64;

  f32x4 acc[4][2];
#pragma unroll
  for (int i = 0; i < 4; i++)
#pragma unroll
    for (int j = 0; j < 2; j++) acc[i][j] = (f32x4){0.f, 0.f, 0.f, 0.f};

  // ---- prologue: stage tile0 and tile1 fully ----
  SA(0, 0, 0); SA(1, 0, 0); SB(0, 0, 0); SB(1, 0, 0);
  if (NT > 1) {
    SA(0, 1, 16384); SA(1, 1, 16384); SB(0, 1, 16384); SB(1, 1, 16384);
    asm volatile("s_waitcnt vmcnt(4)" ::: "memory");
  } else {
    asm volatile("s_waitcnt vmcnt(0)" ::: "memory");
  }
  __builtin_amdgcn_s_barrier();
  asm volatile("" ::: "memory");

  for (int t = 0; t < NT; ++t) {
    const int cb = (t & 1) << 14;   // current buffer base (ushort idx)
    bf16x8 af[4][2], bfr[2][2];
#pragma unroll
    for (int j = 0; j < 2; j++) {
      bfr[j][0] = *(const bf16x8*)&sm[cb + boff + j * 1024 + c80];
      bfr[j][1] = *(const bf16x8*)&sm[cb + boff + j * 1024 + c81];
    }
#pragma unroll
    for (int i = 0; i < 4; i++) {
      af[i][0] = *(const bf16x8*)&sm[cb + aoff + i * 1024 + c80];
      af[i][1] = *(const bf16x8*)&sm[cb + aoff + i * 1024 + c81];
    }
#pragma unroll
    for (int i = 0; i < 4; i++)
#pragma unroll
      for (int j = 0; j < 2; j++) {
        acc[i][j] = __builtin_amdgcn_mfma_f32_16x16x32_bf16(
            bfr[j][0], af[i][0], acc[i][j], 0, 0, 0);
        acc[i][j] = __builtin_amdgcn_mfma_f32_16x16x32_bf16(
            bfr[j][1], af[i][1], acc[i][j], 0, 0, 0);
      }
    // ---- barrier 1: all waves done reading cb ----
    asm volatile("s_waitcnt lgkmcnt(0)" ::: "memory");
    __builtin_amdgcn_s_barrier();
    asm volatile("" ::: "memory");
    // ---- stage tile t+2 into cb; counted wait; barrier 2 ----
    if (t + 2 < NT) {
      SA(0, t + 2, cb); SA(1, t + 2, cb);
      SB(0, t + 2, cb); SB(1, t + 2, cb);
      asm volatile("s_waitcnt vmcnt(4)" ::: "memory");
    } else {
      asm volatile("s_waitcnt vmcnt(0)" ::: "memory");
    }
    __builtin_amdgcn_s_barrier();
    asm volatile("" ::: "memory");
  }
#undef SA
#undef SB

  // ---- epilogue: lane owns row l16, 4 consecutive cols per fragment ----
#pragma unroll
  for (int i = 0; i < 4; i++) {
    const size_t row = (size_t)(bm0 + wm * 64 + i * 16 + l16);
#pragma unroll
    for (int j = 0; j < 2; j++) {
      const int c = bn0 + wn * 32 + j * 16 + quad * 4;
      const float4 bv = *(const float4*)(bias + c);
      const float v0 = acc[i][j][0] + bv.x;
      const float v1 = acc[i][j][1] + bv.y;
      const float v2 = acc[i][j][2] + bv.z;
      const float v3 = acc[i][j][3] + bv.w;
      if (EPI == 0) {
        ushort4 o;
        if (c < 1024) {
          o.x = f2bf(v0 / (1.f + __expf(-v0)));
          o.y = f2bf(v1 / (1.f + __expf(-v1)));
          o.z = f2bf(v2 / (1.f + __expf(-v2)));
          o.w = f2bf(v3 / (1.f + __expf(-v3)));
          *(ushort4*)((ushort*)p0 + row * 1024 + c) = o;
        } else {
          o.x = f2bf(1.f / (1.f + __expf(-v0)));
          o.y = f2bf(1.f / (1.f + __expf(-v1)));
          o.z = f2bf(1.f / (1.f + __expf(-v2)));
          o.w = f2bf(1.f / (1.f + __expf(-v3)));
          *(ushort4*)((ushort*)p1 + row * 1024 + (c - 1024)) = o;
        }
      } else if (EPI == 1) {
        float4* io = (float4*)((float*)p0 + row * 1024 + c);
        float4 t4 = *io;
        t4.x += v0; t4.y += v1; t4.z += v2; t4.w += v3;
        *io = t4;
      } else if (EPI == 2) {
        ushort4 o;
        o.x = f2bf(0.5f * v0 * (1.f + erff(v0 * 0.70710678118654752f)));
        o.y = f2bf(0.5f * v1 * (1.f + erff(v1 * 0.70710678118654752f)));
        o.z = f2bf(0.5f * v2 * (1.f + erff(v2 * 0.70710678118654752f)));
        o.w = f2bf(0.5f * v3 * (1.f + erff(v3 * 0.70710678118654752f)));
        *(ushort4*)((ushort*)p0 + row * 2048 + c) = o;
      } else {
        const float4 pv = *(const float4*)((const float*)p1 + row * 1024 + c);
        float4 t4;
        t4.x = pv.x + v0; t4.y = pv.y + v1;
        t4.z = pv.z + v2; t4.w = pv.w + v3;
        *(float4*)((float*)p0 + row * 1024 + c) = t4;
      }
    }
  }
}

// ---------------------------------------------------------------------------
extern "C" void kernel_launch(void* const* d_in, const int* in_sizes, int n_in,
                              void* d_out, int out_size, void* d_ws,
                              size_t ws_size, hipStream_t stream) {
  const float* x      = (const float*)d_in[0];
  const float* ln1_w  = (const float*)d_in[1];
  const float* ln1_b  = (const float*)d_in[2];
  const float* conv_w = (const float*)d_in[3];
  const float* conv_b = (const float*)d_in[4];
  const float* lns_w  = (const float*)d_in[5];
  const float* lns_b  = (const float*)d_in[6];
  const float* in_w   = (const float*)d_in[7];
  const float* in_b   = (const float*)d_in[8];
  const float* xp_w   = (const float*)d_in[9];
  const float* xp_b   = (const float*)d_in[10];
  const float* A_log  = (const float*)d_in[11];
  const float* Dm     = (const float*)d_in[12];
  const float* out_w  = (const float*)d_in[13];
  const float* out_b  = (const float*)d_in[14];
  const float* ln2_w  = (const float*)d_in[15];
  const float* ln2_b  = (const float*)d_in[16];
  const float* mlp_w1 = (const float*)d_in[17];
  const float* mlp_b1 = (const float*)d_in[18];
  const float* mlp_w2 = (const float*)d_in[19];
  const float* mlp_b2 = (const float*)d_in[20];

  char* wsp = (char*)d_ws;
  size_t off = 0;
  auto alloc = [&](size_t bytes) {
    void* p = wsp + off;
    off += (bytes + 255) & ~(size_t)255;
    return p;
  };
  // 16384 rows x 1024. Aliasing plan (lifetimes disjoint):
  float*  x1    = (float*)alloc(67108864);   // x1 -> x2 (in-place residual)
  ushort* abuf  = (ushort*)alloc(67108864);  // lnS out (dead after GEMM1)
  ushort* gbuf  = abuf + 16777216;           // g (written after GEMM1)
  ushort* xpb   = (ushort*)alloc(33554432);  // xp; later h (ln2 out)
  ushort* zb    = (ushort*)alloc(67108864);  // z bf16 (32MB); later h1 bf16
  ushort* h1b   = (ushort*)zb;
  float*  ub    = (float*)alloc(1048576);
  float*  hsb   = (float*)alloc(1048576);
  float2* stb   = (float2*)alloc(131072);    // 16384 x (mean, rstd)
  ushort* in_wT = (ushort*)alloc(4194304);   // 2048 x 1024
  ushort* out_wT= (ushort*)alloc(2097152);   // 1024 x 1024
  ushort* w1T   = (ushort*)alloc(4194304);   // 2048 x 1024
  ushort* w2T   = (ushort*)alloc(4194304);   // 1024 x 2048

  wt_all_kernel<<<7168, 256, 0, stream>>>(in_w, out_w, mlp_w1, mlp_w2,
                                          in_wT, out_wT, w1T, w2T);
  rowstats_kernel<<<4096, 256, 0, stream>>>(x, stb);
  lnconv_kernel<<<4096, 256, 0, stream>>>(x, stb, ln1_w, ln1_b, conv_w,
                                          conv_b, lns_w, lns_b, x1, abuf);
  gemm_bt<0><<<dim3(128, 16), 512, 0, stream>>>(abuf, in_wT, in_b, 1024,
                                                xpb, zb);
  u_mfma_kernel<<<256, 256, 0, stream>>>(xpb, xp_w, xp_b, ub);
  scan_kernel<<<64, 256, 0, stream>>>(ub, A_log, hsb);
  g_kernel<<<1024, 256, 0, stream>>>(hsb, Dm, zb, gbuf);
  gemm_bt<1><<<dim3(128, 8), 512, 0, stream>>>(gbuf, out_wT, out_b, 1024,
                                               x1, nullptr);
  ln_kernel<1><<<4096, 256, 0, stream>>>(x1, ln2_w, ln2_b, xpb);
  gemm_bt<2><<<dim3(128, 16), 512, 0, stream>>>(xpb, w1T, mlp_b1, 1024,
                                                h1b, nullptr);
  gemm_bt<3><<<dim3(128, 8), 512, 0, stream>>>(h1b, w2T, mlp_b2, 2048,
                                               d_out, x1);
}